// Round 2
// baseline (1449.010 us; speedup 1.0000x reference)
//
#include <hip/hip_runtime.h>

// GNN_19971597927185 — fp32, per-(b,a) fused phi/gamma blocks, chunked over
// batch to fit ws_size (whole network is independent per batch element b).
//
// Workspace layout (floats), chunk size BC batches:
//   r    : (BC, A, 64, U)   BC*262144
//   msgs : (BC, A, 64, U)   BC*262144
//   S    : (BC, 64, U)      BC*4096
//   cgT  : (B, A, U)        524288      (full, all batches)
//   Wt   : transposed weights, 90560

__device__ __forceinline__ float waveSum(float v) {
    v += __shfl_xor(v, 1);
    v += __shfl_xor(v, 2);
    v += __shfl_xor(v, 4);
    v += __shfl_xor(v, 8);
    v += __shfl_xor(v, 16);
    v += __shfl_xor(v, 32);
    return v;
}

// ---------------------------------------------------------------- prep ----
// blocks 0..18: transpose one weight slice (64 x C, o-major) -> (C x 64, c-major)
// blocks 19.. : cgT[(b*64+a)*64 + u] = cg[(b*64+u)*64 + a]
__global__ __launch_bounds__(256) void prep_kernel(
    const float* __restrict__ cg, float* __restrict__ cgT, float* __restrict__ Wt,
    const float* __restrict__ phi1_W1, const float* __restrict__ phi1_W2,
    const float* __restrict__ phiK_W1, const float* __restrict__ phiK_W2,
    const float* __restrict__ g1_W1,   const float* __restrict__ g1_W2,
    const float* __restrict__ gK_W1,   const float* __restrict__ gK_W2,
    const float* __restrict__ g5_W1)
{
    const int bid = blockIdx.x;
    const int t = threadIdx.x;
    if (bid < 19) {
        const float* src; int C; int dst;
        if (bid == 0)       { src = phi1_W1;                 C = 2;   dst = 0; }
        else if (bid == 1)  { src = phi1_W2;                 C = 64;  dst = 128; }
        else if (bid < 6)   { int k = bid - 2;  src = phiK_W1 + k*4160; C = 65;  dst = 4224  + k*4160; }
        else if (bid < 10)  { int k = bid - 6;  src = phiK_W2 + k*4096; C = 64;  dst = 20864 + k*4096; }
        else if (bid == 10) { src = g1_W1;                   C = 65;  dst = 37248; }
        else if (bid == 11) { src = g1_W2;                   C = 64;  dst = 41408; }
        else if (bid < 15)  { int k = bid - 12; src = gK_W1 + k*8192;  C = 128; dst = 45504 + k*8192; }
        else if (bid < 18)  { int k = bid - 15; src = gK_W2 + k*4096;  C = 64;  dst = 70080 + k*4096; }
        else                { src = g5_W1;                   C = 128; dst = 82368; }
        for (int e = t; e < 64 * C; e += 256) {
            int o = e / C;
            int c = e - o * C;
            Wt[dst + c * 64 + o] = src[o * C + c];
        }
    } else {
        int idx = (bid - 19) * 256 + t;          // (b, a, u)
        int b = idx >> 12;
        int rem = idx & 4095;
        int a = rem >> 6;
        int u = rem & 63;
        cgT[idx] = cg[((b << 6) + u) * 64 + a];
    }
}

// ----------------------------------------------------------------- phi ----
// One block per (b,a) within the chunk. Lane = u; wave g owns rows [16g,16g+16).
template <bool FIRST>
__global__ __launch_bounds__(256) void phi_kernel(
    const float* __restrict__ cgT,
    const float* __restrict__ r,
    const float* __restrict__ W1t, const float* __restrict__ b1,
    const float* __restrict__ W2t, const float* __restrict__ b2,
    float* __restrict__ msgs)
{
    __shared__ float hbuf[64 * 64];
    const int bid = blockIdx.x;
    const int t = threadIdx.x;
    const int u = t & 63;
    const int g = __builtin_amdgcn_readfirstlane(t >> 6);
    const int o0 = g * 16;
    constexpr float inv63 = 1.0f / 63.0f;

    float acc[16];
#pragma unroll
    for (int j = 0; j < 16; ++j) acc[j] = b1[o0 + j];

    const float cgv = cgT[bid * 64 + u];
    if (FIRST) {
        // x = [cg, cg], C=2
#pragma unroll
        for (int c = 0; c < 2; ++c) {
            const float* wrow = W1t + c * 64 + o0;
#pragma unroll
            for (int j = 0; j < 16; ++j) acc[j] += wrow[j] * cgv;
        }
    } else {
        {
            const float* wrow = W1t + o0;   // channel 0 = cg
#pragma unroll
            for (int j = 0; j < 16; ++j) acc[j] += wrow[j] * cgv;
        }
        const float* rSlab = r + (size_t)bid * 4096;
#pragma unroll 4
        for (int c = 0; c < 64; ++c) {
            float xv = rSlab[c * 64 + u];
            const float* wrow = W1t + (c + 1) * 64 + o0;
#pragma unroll
            for (int j = 0; j < 16; ++j) acc[j] += wrow[j] * xv;
        }
    }
    // relu + post_users (rows >= 32 replaced by (rowsum - self)/63)
#pragma unroll
    for (int j = 0; j < 16; ++j) acc[j] = fmaxf(acc[j], 0.0f);
    if (g >= 2) {
#pragma unroll
        for (int j = 0; j < 16; ++j) {
            float s = waveSum(acc[j]);
            acc[j] = (s - acc[j]) * inv63;
        }
    }
#pragma unroll
    for (int j = 0; j < 16; ++j) hbuf[(o0 + j) * 64 + u] = acc[j];
    __syncthreads();

    // layer 2
    float acc2[16];
#pragma unroll
    for (int j = 0; j < 16; ++j) acc2[j] = b2[o0 + j];
#pragma unroll 4
    for (int c = 0; c < 64; ++c) {
        float xv = hbuf[c * 64 + u];
        const float* wrow = W2t + c * 64 + o0;
#pragma unroll
        for (int j = 0; j < 16; ++j) acc2[j] += wrow[j] * xv;
    }
    // post_users (no relu), write msgs
    if (g >= 2) {
#pragma unroll
        for (int j = 0; j < 16; ++j) {
            float s = waveSum(acc2[j]);
            acc2[j] = (s - acc2[j]) * inv63;
        }
    }
    float* mSlab = msgs + (size_t)bid * 4096;
#pragma unroll
    for (int j = 0; j < 16; ++j) mSlab[(o0 + j) * 64 + u] = acc2[j];
}

// -------------------------------------------------------------- reduce ----
// S[b, c, u] = sum_a msgs[b, a, c, u]   (b local to chunk)
__global__ __launch_bounds__(256) void reduce_kernel(
    const float* __restrict__ msgs, float* __restrict__ S)
{
    int idx = blockIdx.x * 256 + threadIdx.x;   // b*4096 + (c*64+u)
    int b = idx >> 12;
    int cu = idx & 4095;
    const float* p = msgs + (size_t)b * 262144 + cu;
    float s = 0.0f;
#pragma unroll 8
    for (int a = 0; a < 64; ++a) s += p[a * 4096];
    S[idx] = s;
}

// --------------------------------------------------------------- gamma ----
// F = feats channels (1 first iter, 64 after).
// x = [feats | agg], agg[c][u] = (S[b,c,u] - msgs[b,a,c,u]) / 63
template <int F, bool FINAL>
__global__ __launch_bounds__(256) void gamma_kernel(
    const float* __restrict__ feats,
    const float* __restrict__ msgs,
    const float* __restrict__ S,
    const float* __restrict__ W1t, const float* __restrict__ b1,
    const float* __restrict__ W2t, const float* __restrict__ b2,  // FINAL: raw (1,64) W2, scalar b2
    float* __restrict__ out)
{
    __shared__ float hbuf[64 * 64];
    __shared__ float part[256];
    const int bid = blockIdx.x;
    const int b = bid >> 6;
    const int a = bid & 63;
    const int t = threadIdx.x;
    const int u = t & 63;
    const int g = __builtin_amdgcn_readfirstlane(t >> 6);
    const int o0 = g * 16;
    constexpr float inv63 = 1.0f / 63.0f;

    const float* mSlab = msgs + (size_t)bid * 4096;
    const float* Sb = S + (size_t)b * 4096;

    float acc[16];
#pragma unroll
    for (int j = 0; j < 16; ++j) acc[j] = b1[o0 + j];

    if (F == 1) {
        float xv = feats[bid * 64 + u];
        const float* wrow = W1t + o0;
#pragma unroll
        for (int j = 0; j < 16; ++j) acc[j] += wrow[j] * xv;
    } else {
        const float* fSlab = feats + (size_t)bid * 4096;
#pragma unroll 4
        for (int c = 0; c < 64; ++c) {
            float xv = fSlab[c * 64 + u];
            const float* wrow = W1t + c * 64 + o0;
#pragma unroll
            for (int j = 0; j < 16; ++j) acc[j] += wrow[j] * xv;
        }
    }
    // agg channels
#pragma unroll 4
    for (int c = 0; c < 64; ++c) {
        float xv = (Sb[c * 64 + u] - mSlab[c * 64 + u]) * inv63;
        const float* wrow = W1t + (F + c) * 64 + o0;
#pragma unroll
        for (int j = 0; j < 16; ++j) acc[j] += wrow[j] * xv;
    }
    // relu + post_users -> p in hbuf
#pragma unroll
    for (int j = 0; j < 16; ++j) acc[j] = fmaxf(acc[j], 0.0f);
    if (g >= 2) {
#pragma unroll
        for (int j = 0; j < 16; ++j) {
            float s = waveSum(acc[j]);
            acc[j] = (s - acc[j]) * inv63;
        }
    }
#pragma unroll
    for (int j = 0; j < 16; ++j) hbuf[(o0 + j) * 64 + u] = acc[j];
    __syncthreads();

    if (FINAL) {
        // h2[u] = b2 + sum_c W2[0,c] * p[c][u]; split c over the 4 waves
        float s = 0.0f;
#pragma unroll
        for (int cc = 0; cc < 16; ++cc) {
            int c = o0 + cc;
            s += W2t[c] * hbuf[c * 64 + u];
        }
        part[t] = s;
        __syncthreads();
        if (t < 64) {
            float h2 = b2[0] + part[t] + part[64 + t] + part[128 + t] + part[192 + t];
            out[((size_t)b * 64 + t) * 64 + a] = h2;   // out[b, 0, u=t, a], b local; out ptr pre-offset
        }
    } else {
        float acc2[16];
#pragma unroll
        for (int j = 0; j < 16; ++j) acc2[j] = b2[o0 + j];
#pragma unroll 4
        for (int c = 0; c < 64; ++c) {
            float xv = hbuf[c * 64 + u];
            const float* wrow = W2t + c * 64 + o0;
#pragma unroll
            for (int j = 0; j < 16; ++j) acc2[j] += wrow[j] * xv;
        }
        // relu then post_users
#pragma unroll
        for (int j = 0; j < 16; ++j) acc2[j] = fmaxf(acc2[j], 0.0f);
        if (g >= 2) {
#pragma unroll
            for (int j = 0; j < 16; ++j) {
                float s = waveSum(acc2[j]);
                acc2[j] = (s - acc2[j]) * inv63;
            }
        }
        float* oSlab = out + (size_t)bid * 4096;
#pragma unroll
        for (int j = 0; j < 16; ++j) oSlab[(o0 + j) * 64 + u] = acc2[j];
    }
}

// -------------------------------------------------------------- launch ----
extern "C" void kernel_launch(void* const* d_in, const int* in_sizes, int n_in,
                              void* d_out, int out_size, void* d_ws, size_t ws_size,
                              hipStream_t stream) {
    const float* cg      = (const float*)d_in[0];
    const float* phi1_W1 = (const float*)d_in[1];
    const float* phi1_b1 = (const float*)d_in[2];
    const float* phi1_W2 = (const float*)d_in[3];
    const float* phi1_b2 = (const float*)d_in[4];
    const float* phiK_W1 = (const float*)d_in[5];
    const float* phiK_b1 = (const float*)d_in[6];
    const float* phiK_W2 = (const float*)d_in[7];
    const float* phiK_b2 = (const float*)d_in[8];
    const float* g1_W1   = (const float*)d_in[9];
    const float* g1_b1   = (const float*)d_in[10];
    const float* g1_W2   = (const float*)d_in[11];
    const float* g1_b2   = (const float*)d_in[12];
    const float* gK_W1   = (const float*)d_in[13];
    const float* gK_b1   = (const float*)d_in[14];
    const float* gK_W2   = (const float*)d_in[15];
    const float* gK_b2   = (const float*)d_in[16];
    const float* g5_W1   = (const float*)d_in[17];
    const float* g5_b1   = (const float*)d_in[18];
    const float* g5_W2   = (const float*)d_in[19];
    const float* g5_b2   = (const float*)d_in[20];
    (void)in_sizes; (void)n_in; (void)out_size;

    // Pick the largest batch-chunk BC (power of two, <=128) whose workspace
    // footprint fits ws_size. Footprint (floats):
    //   r: BC*262144, msgs: BC*262144, S: BC*4096, cgT: 524288, Wt: 90560
    int BC = 128;
    while (BC > 4) {
        size_t needFloats = (size_t)BC * 262144 * 2 + (size_t)BC * 4096 + 524288 + 90560;
        if (needFloats * 4 <= ws_size) break;
        BC >>= 1;
    }
    const int NC = 128 / BC;

    float* ws   = (float*)d_ws;
    float* r    = ws;
    float* msgs = r + (size_t)BC * 262144;
    float* S    = msgs + (size_t)BC * 262144;
    float* cgT  = S + (size_t)BC * 4096;
    float* Wt   = cgT + 524288;
    float* out  = (float*)d_out;

    prep_kernel<<<19 + 2048, 256, 0, stream>>>(cg, cgT, Wt,
        phi1_W1, phi1_W2, phiK_W1, phiK_W2, g1_W1, g1_W2, gK_W1, gK_W2, g5_W1);

    const int nblk = BC * 64;        // (b,a) fibers per chunk
    const int rblk = BC * 16;        // reduce blocks per chunk

    for (int c = 0; c < NC; ++c) {
        const float* cgTc = cgT + (size_t)c * BC * 4096;
        float* outc = out + (size_t)c * BC * 4096;

        // iteration 0: phi1 + gamma1
        phi_kernel<true><<<nblk, 256, 0, stream>>>(cgTc, nullptr,
            Wt + 0, phi1_b1, Wt + 128, phi1_b2, msgs);
        reduce_kernel<<<rblk, 256, 0, stream>>>(msgs, S);
        gamma_kernel<1, false><<<nblk, 256, 0, stream>>>(cgTc, msgs, S,
            Wt + 37248, g1_b1, Wt + 41408, g1_b2, r);

        // iterations 1..4: phiK[k] + (gammaK[k] or gamma5)
        for (int k = 0; k < 4; ++k) {
            phi_kernel<false><<<nblk, 256, 0, stream>>>(cgTc, r,
                Wt + 4224 + k * 4160, phiK_b1 + k * 64,
                Wt + 20864 + k * 4096, phiK_b2 + k * 64, msgs);
            reduce_kernel<<<rblk, 256, 0, stream>>>(msgs, S);
            if (k < 3) {
                gamma_kernel<64, false><<<nblk, 256, 0, stream>>>(r, msgs, S,
                    Wt + 45504 + k * 8192, gK_b1 + k * 64,
                    Wt + 70080 + k * 4096, gK_b2 + k * 64, r);
            } else {
                gamma_kernel<64, true><<<nblk, 256, 0, stream>>>(r, msgs, S,
                    Wt + 82368, g5_b1, g5_W2, g5_b2, outc);
            }
        }
    }
}